// Round 7
// baseline (158.067 us; speedup 1.0000x reference)
//
#include <hip/hip_runtime.h>
#include <hip/hip_fp16.h>
#include <math.h>

#define N    20000
#define E    200000
#define EP   220000   // E + N self loops
#define F_IN 23
#define D1   960
#define H1   8
#define C1   120
#define KPL  15       // real channels per lane
#define PC   16       // padded channels per lane
#define ROW  1024     // halves per node row (2048 B)

typedef _Float16 f16x2 __attribute__((ext_vector_type(2)));

__device__ inline float fdot2(__half2 a, __half2 b, float c) {
#if __has_builtin(__builtin_amdgcn_fdot2)
  f16x2 av, bv;
  __builtin_memcpy(&av, &a, 4);
  __builtin_memcpy(&bv, &b, 4);
  return __builtin_amdgcn_fdot2(av, bv, c, false);
#else
  float2 af = __half22float2(a), bf = __half22float2(b);
  return fmaf(af.x, bf.x, fmaf(af.y, bf.y, c));
#endif
}

// packed half2 max (ROCm 7.2 lacks __hmax2) -> v_pk_max_f16
__device__ inline __half2 hmax2(__half2 a, __half2 b) {
  f16x2 av, bv;
  __builtin_memcpy(&av, &a, 4);
  __builtin_memcpy(&bv, &b, 4);
  f16x2 rv = __builtin_elementwise_max(av, bv);
  __half2 r;
  __builtin_memcpy(&r, &rv, 4);
  return r;
}

// ---------------- fused: transform1 (blocks 0..T1_BLOCKS) + count ----------
#define T1_BLOCKS 500
#define T1_NPB    40
#define T1_TILE   20
#define CNT_BLOCKS 430   // ceil(EP/512)
__global__ __launch_bounds__(512, 4)
void k_t1_count(const float* __restrict__ x,
                const float* __restrict__ W1l, const float* __restrict__ b1l,
                const float* __restrict__ W1r, const float* __restrict__ b1r,
                __half* __restrict__ xl1, __half* __restrict__ xr1,
                const int* __restrict__ ei, int* __restrict__ deg) {
  int tid = threadIdx.x;
  if (blockIdx.x >= T1_BLOCKS) {
    int id = (blockIdx.x - T1_BLOCKS) * 512 + tid;
    if (id < EP) {
      int dst = (id < E) ? ei[E + id] : (id - E);
      atomicAdd(&deg[dst], 1);
    }
    return;
  }
  int rlane = tid >> 3, kp = tid & 7;
  int c0 = (rlane >> 3) * C1 + (rlane & 7) * KPL + 2 * kp;
  bool hasK1 = (kp < 7);
  float wl0[F_IN], wl1[F_IN], wr0[F_IN], wr1[F_IN];
#pragma unroll
  for (int f = 0; f < F_IN; f++) {
    wl0[f] = W1l[f * D1 + c0];
    wr0[f] = W1r[f * D1 + c0];
    wl1[f] = hasK1 ? W1l[f * D1 + c0 + 1] : 0.f;
    wr1[f] = hasK1 ? W1r[f * D1 + c0 + 1] : 0.f;
  }
  float bl0 = b1l[c0], br0 = b1r[c0];
  float bl1 = hasK1 ? b1l[c0 + 1] : 0.f;
  float br1 = hasK1 ? b1r[c0 + 1] : 0.f;

  __shared__ float xs[T1_TILE][F_IN];
  int nbase = blockIdx.x * T1_NPB;
  unsigned int* xl1u = (unsigned int*)xl1;
  unsigned int* xr1u = (unsigned int*)xr1;
  for (int t = 0; t < T1_NPB; t += T1_TILE) {
    if (tid < T1_TILE * F_IN) {
      int n = tid / F_IN, f = tid - n * F_IN;
      xs[n][f] = x[(size_t)(nbase + t + n) * F_IN + f];
    }
    __syncthreads();
    for (int n = 0; n < T1_TILE; n++) {
      float a0 = bl0, a1 = bl1, r0 = br0, r1 = br1;
#pragma unroll
      for (int f = 0; f < F_IN; f++) {
        float xv = xs[n][f];
        a0 = fmaf(xv, wl0[f], a0);
        a1 = fmaf(xv, wl1[f], a1);
        r0 = fmaf(xv, wr0[f], r0);
        r1 = fmaf(xv, wr1[f], r1);
      }
      size_t o = (size_t)(nbase + t + n) * 512 + tid;
      unsigned int ul = ((unsigned int)__half_as_ushort(__float2half(a1)) << 16)
                      | __half_as_ushort(__float2half(a0));
      unsigned int ur = ((unsigned int)__half_as_ushort(__float2half(r1)) << 16)
                      | __half_as_ushort(__float2half(r0));
      __builtin_nontemporal_store(ul, &xl1u[o]);
      __builtin_nontemporal_store(ur, &xr1u[o]);
    }
    __syncthreads();
  }
}

// ---------------- scan: whole deg[] in LDS, 20 elems/thread ----------------
#define SC_TOT 20480   // 1024 * 20
__global__ __launch_bounds__(1024)
void k_scan(const int* __restrict__ deg, int* __restrict__ off,
            int* __restrict__ cursor) {
  __shared__ int buf[SC_TOT];
  __shared__ int parts[1024];
  __shared__ int wsum[17];
  int tid = threadIdx.x;
  for (int i = tid; i < SC_TOT; i += 1024) buf[i] = (i < N) ? deg[i] : 0;
  __syncthreads();
  int base = tid * 20;
  int loc[20];
  int run = 0;
#pragma unroll
  for (int e = 0; e < 20; e++) { loc[e] = run; run += buf[base + e]; }
  parts[tid] = run;
  __syncthreads();
  int lane = tid & 63, wid = tid >> 6;
  int v = parts[tid];
  int incl = v;
#pragma unroll
  for (int d = 1; d < 64; d <<= 1) {
    int t = __shfl_up(incl, d, 64);
    if (lane >= d) incl += t;
  }
  if (lane == 63) wsum[wid] = incl;
  __syncthreads();
  if (tid == 0) {
    int acc = 0;
#pragma unroll
    for (int w = 0; w < 16; w++) { int t = wsum[w]; wsum[w] = acc; acc += t; }
    wsum[16] = acc;
  }
  __syncthreads();
  int texcl = incl - v + wsum[wid];
#pragma unroll
  for (int e = 0; e < 20; e++) buf[base + e] = texcl + loc[e];
  __syncthreads();
  for (int i = tid; i < N; i += 1024) {
    int t = buf[i];
    off[i] = t;
    cursor[i] = t;
  }
  if (tid == 0) off[N] = wsum[16];
}

// scatter: store src node id directly
__global__ __launch_bounds__(512)
void k_scatter(const int* __restrict__ ei, int* __restrict__ cursor,
               int* __restrict__ srcs) {
  int id = blockIdx.x * 512 + threadIdx.x;
  if (id >= EP) return;
  int dst, src;
  if (id < E) { dst = ei[E + id]; src = ei[id]; }
  else        { dst = id - E;     src = id - E; }
  int pos = atomicAdd(&cursor[dst], 1);
  srcs[pos] = src;
}

// ---------------- fused layer1 aggregate + relu + layer2 transform ----------
// 128-thread blocks (2 waves, 1 node each): finer retirement granularity for
// load balance (R6: 4-wave blocks, occupancy 56%). Depth-3 row prefetch.
union Rowu {
  uint4 u[2];
  __half2 h[8];
};

__global__ __launch_bounds__(128, 6)
void k_l1agg(const int* __restrict__ off, const int* __restrict__ srcs,
             const __half* __restrict__ xl1, const __half* __restrict__ xr1,
             const float* __restrict__ att1, const float* __restrict__ bias1,
             const float* __restrict__ W2l, const float* __restrict__ b2l,
             const float* __restrict__ W2r, const float* __restrict__ b2r,
             float* __restrict__ xl2, float* __restrict__ xr2) {
  int node = blockIdx.x * 2 + (threadIdx.x >> 6);
  if (node >= N) return;
  int lane = threadIdx.x & 63;
  int cbase = (lane >> 3) * C1 + (lane & 7) * KPL;

  Rowu xr;
  {
    const uint4* rp = (const uint4*)(xr1 + ((size_t)node << 10)) + (lane << 1);
    xr.u[0] = rp[0]; xr.u[1] = rp[1];
  }
  __half2 at2[8];
#pragma unroll
  for (int j = 0; j < 7; j++)
    at2[j] = __floats2half2_rn(att1[cbase + 2 * j], att1[cbase + 2 * j + 1]);
  at2[7] = __floats2half2_rn(att1[cbase + 14], 0.f);

  const __half2 c02 = __float2half2_rn(0.2f);
  __half2 o2[8];
#pragma unroll
  for (int j = 0; j < 8; j++) o2[j] = __float2half2_rn(0.f);
  float m = -INFINITY, d = 0.f;

  int p0 = off[node], p1 = off[node + 1];
  // depth-3 software pipeline (every node has >=1 edge: self loop)
  int sA = srcs[p0];
  int sB = srcs[(p0 + 1 < p1) ? p0 + 1 : p1 - 1];
  int sC = srcs[(p0 + 2 < p1) ? p0 + 2 : p1 - 1];
  Rowu rA, rB, rC;
  {
    const uint4* pa = (const uint4*)(xl1 + ((size_t)sA << 10)) + (lane << 1);
    rA.u[0] = pa[0]; rA.u[1] = pa[1];
    const uint4* pb = (const uint4*)(xl1 + ((size_t)sB << 10)) + (lane << 1);
    rB.u[0] = pb[0]; rB.u[1] = pb[1];
    const uint4* pc = (const uint4*)(xl1 + ((size_t)sC << 10)) + (lane << 1);
    rC.u[0] = pc[0]; rC.u[1] = pc[1];
  }

  for (int p = p0; p < p1; p++) {
    Rowu cur = rA;
    rA = rB; rB = rC;
    int pn = (p + 3 < p1) ? p + 3 : p1 - 1;
    int sn = srcs[pn];
    const uint4* np = (const uint4*)(xl1 + ((size_t)sn << 10)) + (lane << 1);
    rC.u[0] = np[0]; rC.u[1] = np[1];

    float pe = 0.f;
#pragma unroll
    for (int j = 0; j < 8; j++) {
      __half2 s = __hadd2(cur.h[j], xr.h[j]);
      __half2 l = hmax2(s, __hmul2(c02, s));   // leaky = max(s, 0.2s)
      pe = fdot2(l, at2[j], pe);
    }
    pe += __shfl_xor(pe, 1, 64);
    pe += __shfl_xor(pe, 2, 64);
    pe += __shfl_xor(pe, 4, 64);
    if (pe > m) {
      float sc = __expf(m - pe);   // m=-inf first edge -> 0
      d *= sc;
      __half2 s2 = __float2half2_rn(sc);
#pragma unroll
      for (int j = 0; j < 8; j++) o2[j] = __hmul2(o2[j], s2);
      m = pe;
    }
    float w = __expf(pe - m);
    d += w;
    __half2 w2 = __float2half2_rn(w);
#pragma unroll
    for (int j = 0; j < 8; j++) o2[j] = __hfma2(w2, cur.h[j], o2[j]);
  }

  float inv = 1.f / (d + 1e-16f);
  float pl = 0.f, pr = 0.f;
#pragma unroll
  for (int j = 0; j < 8; j++) {
    float2 of = __half22float2(o2[j]);
    int k0 = 2 * j;
    float hv = fmaf(of.x, inv, bias1[cbase + k0]);
    hv = fmaxf(hv, 0.f);
    pl = fmaf(hv, W2l[cbase + k0], pl);
    pr = fmaf(hv, W2r[cbase + k0], pr);
    if (j < 7) {
      float hv2 = fmaf(of.y, inv, bias1[cbase + k0 + 1]);
      hv2 = fmaxf(hv2, 0.f);
      pl = fmaf(hv2, W2l[cbase + k0 + 1], pl);
      pr = fmaf(hv2, W2r[cbase + k0 + 1], pr);
    }
  }
#pragma unroll
  for (int dx = 1; dx < 64; dx <<= 1) {
    pl += __shfl_xor(pl, dx, 64);
    pr += __shfl_xor(pr, dx, 64);
  }
  if (lane == 0) {
    xl2[node] = pl + b2l[0];
    xr2[node] = pr + b2r[0];
  }
}

// ---------------- layer 2 aggregate ----------------
__global__ void k_l2agg(const int* __restrict__ off, const int* __restrict__ srcs,
                        const float* __restrict__ xl2, const float* __restrict__ xr2,
                        const float* __restrict__ att2, const float* __restrict__ bias2,
                        float* __restrict__ out) {
  int node = blockIdx.x * blockDim.x + threadIdx.x;
  if (node >= N) return;
  float xr = xr2[node];
  float a2 = att2[0];
  float m = -INFINITY, d = 0.f, o = 0.f;
  int p1 = off[node + 1];
  for (int p = off[node]; p < p1; p++) {
    float xl = xl2[srcs[p]];
    float s = xl + xr;
    s = fmaxf(s, 0.2f * s);
    float e = s * a2;
    if (e > m) { float sc = __expf(m - e); d *= sc; o *= sc; m = e; }
    float w = __expf(e - m);
    d += w;
    o = fmaf(w, xl, o);
  }
  out[node] = o / (d + 1e-16f) + bias2[0];
}

extern "C" void kernel_launch(void* const* d_in, const int* in_sizes, int n_in,
                              void* d_out, int out_size, void* d_ws, size_t ws_size,
                              hipStream_t stream) {
  const float* x     = (const float*)d_in[0];
  const int*   ei    = (const int*)d_in[1];
  const float* W1l   = (const float*)d_in[2];
  const float* b1l   = (const float*)d_in[3];
  const float* W1r   = (const float*)d_in[4];
  const float* b1r   = (const float*)d_in[5];
  const float* att1  = (const float*)d_in[6];
  const float* bias1 = (const float*)d_in[7];
  const float* W2l   = (const float*)d_in[8];
  const float* b2l   = (const float*)d_in[9];
  const float* W2r   = (const float*)d_in[10];
  const float* b2r   = (const float*)d_in[11];
  const float* att2  = (const float*)d_in[12];
  const float* bias2 = (const float*)d_in[13];
  float* out = (float*)d_out;

  char* ws = (char*)d_ws;
  size_t off_b = 0;
  auto alloc = [&](size_t bytes) {
    size_t cur = off_b;
    off_b += (bytes + 255) & ~(size_t)255;
    return (void*)(ws + cur);
  };
  __half* xl1 = (__half*)alloc((size_t)N * ROW * sizeof(__half));
  __half* xr1 = (__half*)alloc((size_t)N * ROW * sizeof(__half));
  int*   deg  = (int*)alloc((size_t)N * sizeof(int));
  int*   offp = (int*)alloc((size_t)(N + 1) * sizeof(int));
  int*   curs = (int*)alloc((size_t)N * sizeof(int));
  int*   srcs = (int*)alloc((size_t)EP * sizeof(int));
  float* xl2  = (float*)alloc((size_t)N * sizeof(float));
  float* xr2  = (float*)alloc((size_t)N * sizeof(float));
  (void)ws_size; (void)in_sizes; (void)n_in; (void)out_size;

  (void)hipMemsetAsync(deg, 0, (size_t)N * sizeof(int), stream);

  k_t1_count<<<T1_BLOCKS + CNT_BLOCKS, 512, 0, stream>>>(
      x, W1l, b1l, W1r, b1r, xl1, xr1, ei, deg);

  k_scan<<<1, 1024, 0, stream>>>(deg, offp, curs);
  k_scatter<<<(EP + 511) / 512, 512, 0, stream>>>(ei, curs, srcs);

  k_l1agg<<<(N + 1) / 2, 128, 0, stream>>>(
      offp, srcs, xl1, xr1, att1, bias1, W2l, b2l, W2r, b2r, xl2, xr2);

  k_l2agg<<<(N + 255) / 256, 256, 0, stream>>>(
      offp, srcs, xl2, xr2, att2, bias2, out);
}